// Round 13
// baseline (329.081 us; speedup 1.0000x reference)
//
#include <hip/hip_runtime.h>
#include <hip/hip_bf16.h>
#include <math.h>

// Problem constants
#define B_    32
#define IC    512
#define OC    256
#define HW    32
#define OHW   64

// ws layout:
//   xcl  at offset 0:          bf16 [32][34][34][512]  = 37,879,808 B (zero-padded channels-last)
//   Amat at offset 37,879,808: bf16 [1024][4608]       =  9,437,184 B
#define WS_AMAT_OFF 37879808ull

typedef __attribute__((ext_vector_type(8))) short short8;
typedef __attribute__((ext_vector_type(4))) float f32x4;
typedef __attribute__((ext_vector_type(2))) float f32x2;

#define GPTR(x) ((const __attribute__((address_space(1))) char*)(x))
#define LPTR(x) ((__attribute__((address_space(3))) char*)(x))

// ---------------------------------------------------------------------------
// Weight transform. M-row order (oc*4 + p): 4 consecutive C-rows per lane are
// the 4 parities of one oc -> coalesced 2x2 output quads in the epilogue.
__global__ __launch_bounds__(256) void wtrans(const float* __restrict__ w,
                                              __hip_bfloat16* __restrict__ Amat) {
    int t = blockIdx.x * blockDim.x + threadIdx.x;  // 131072 threads
    int ic = t & 511, oc = t >> 9;

    const float gain = 1.0f / sqrtf((float)(IC * 9));
    float wl[3][3];
    const float* wp = w + ((size_t)oc * IC + ic) * 9;
#pragma unroll
    for (int i = 0; i < 3; ++i)
#pragma unroll
        for (int j = 0; j < 3; ++j) wl[i][j] = wp[i * 3 + j] * gain;

    const float f1[4] = {1.f, 3.f, 3.f, 1.f};
    float g2[6][6];
#pragma unroll
    for (int s = 0; s < 6; ++s)
#pragma unroll
        for (int tt = 0; tt < 6; ++tt) {
            float acc = 0.f;
#pragma unroll
            for (int i = 0; i < 3; ++i)
#pragma unroll
                for (int j = 0; j < 3; ++j) {
                    int a = s - 2 + i, b = tt - 2 + j;
                    if (a >= 0 && a < 4 && b >= 0 && b < 4)
                        acc += wl[i][j] * f1[a] * f1[b] * 0.0625f;
                }
            g2[s][tt] = acc;
        }

#pragma unroll
    for (int pm = 0; pm < 2; ++pm)
#pragma unroll
        for (int pn = 0; pn < 2; ++pn)
#pragma unroll
            for (int k = 0; k < 3; ++k)
#pragma unroll
                for (int l = 0; l < 3; ++l) {
                    int p = pm * 2 + pn;
                    size_t idx = ((size_t)(oc * 4 + p) * 4608) + (k * 3 + l) * 512 + ic;
                    Amat[idx] = __float2bfloat16(g2[2 * k + 1 - pm][2 * l + 1 - pn]);
                }
}

// ---------------------------------------------------------------------------
// x (fp32 NCHW) -> xcl (bf16, [b][34][34][512], zero halo), via LDS transpose.
__global__ __launch_bounds__(256) void xprep(const float* __restrict__ x,
                                             __hip_bfloat16* __restrict__ xcl) {
    int blk = blockIdx.x;            // 32*34 blocks
    int b = blk / 34, h = blk % 34;
    __hip_bfloat16* orow = xcl + (size_t)(b * 34 + h) * 34 * 512;
    int t = threadIdx.x;
    bool hin = (h >= 1 && h <= 32);

    for (int i = t; i < 2 * 512; i += 256) {
        int wsel = i >> 9, ic = i & 511;
        orow[(size_t)(wsel * 33) * 512 + ic] = __float2bfloat16(0.f);
    }

    __shared__ float ls[16][33];
    int icl_r = t >> 5, wv_r = t & 31;
    int wv_w = t >> 3, icl_w = t & 7;

    for (int ic0 = 0; ic0 < 512; ic0 += 16) {
        __syncthreads();
#pragma unroll
        for (int pp = 0; pp < 2; ++pp) {
            int icll = icl_r + pp * 8;
            float v = 0.f;
            if (hin) v = x[(((size_t)b * IC + ic0 + icll) * HW + (h - 1)) * HW + wv_r];
            ls[icll][wv_r] = v;
        }
        __syncthreads();
#pragma unroll
        for (int pp = 0; pp < 2; ++pp) {
            int icll = icl_w + pp * 8;
            orow[(size_t)(wv_w + 1) * 512 + ic0 + icll] = __float2bfloat16(ls[icll][wv_w]);
        }
    }
}

// ---------------------------------------------------------------------------
// Implicit-GEMM, 256x128 tile, BK=32, 4 waves (2Mx2N), dbuf-2 LDS = 48 KB
// -> 2 BLOCKS/CU (R13's lever): occupancy 22%->~44%. The two co-resident
// blocks have independent barriers, so one block's MFMA phase overlaps the
// other's LDS-read phase — the cross-block overlap every single-block
// schedule (R4/R5/R6/R8/R11) could not create (all 8 waves barrier-locked
// into the same phase at 1 block/CU).
// 16x16x32 engine + R4's VERIFIED zero-conflict swizzle (g ^ ((r>>1)&3));
// the 32x32 engine line (R8/R12) is abandoned: its 2.83e7 residual conflict
// count was invariant to swizzle changes -> unmodeled HW interaction.
// Counted vmcnt(6), distance-1 dbuf, 2 barriers/tile, T5 setprio, XCD remap.
//
// LDS buffer (24 KB): A[256 rows][64 B] (16 KB) then B[128 rows][64 B] (8 KB).
// Race safety: barrier #1 (top) separates iter t-1's ds_reads of buf
// (t+1)&1 from STAGE(t+1) overwriting it; vmcnt(6)+barrier #2 guarantees
// every wave's tile-t planes landed before any wave reads them.
__global__ __launch_bounds__(256, 2) void gemm_conv(const __hip_bfloat16* __restrict__ Amat,
                                                    const __hip_bfloat16* __restrict__ xcl,
                                                    const float* __restrict__ bias,
                                                    float* __restrict__ out) {
    __shared__ __align__(1024) char lds[2 * 24576];

    const int NT = 144;              // K-tiles of 32 (K = 4608)
    int bid = blockIdx.x;            // 1024 blocks
    // XCD remap: xcd = bid&7 owns nt slab [xcd*32, +32); mt = (bid>>3)&3 puts
    // all 4 mt of a slab co-resident on that XCD (B-panel L2-shared);
    // bid>>5 sweeps nt within the slab (A-panel L2-hot). Bijective.
    int mt = (bid >> 3) & 3;                       // 0..3
    int nt = (bid & 7) * 32 + (bid >> 5);          // 0..255 (N-tile of 128)
    int tid = threadIdx.x;           // 256 threads = 4 waves
    int wid = tid >> 6;
    int lane = tid & 63;
    int wr = wid >> 1;               // 0..1  (M half: rows wr*128..+127)
    int wc = wid & 1;                // 0..1  (N half: cols wc*64..+63)
    int q = lane >> 4;               // k-granule
    int lr = lane & 15;

    // ---- staging constants (swizzle folded into global source) ----
    int r0 = tid >> 2;               // 0..63 (chunk i adds i*64)
    int slt = tid & 3;               // LDS slot in 64-B row
    int g_ = slt ^ ((r0 >> 1) & 3);  // i*64 doesn't touch bits 1-2 of row

    const char* GA = (const char*)Amat;
    const char* GB = (const char*)xcl;

    size_t asrcb = (size_t)(mt * 256 + r0) * 9216 + g_ * 16;  // + i*64*9216
    int bsrc[2];
#pragma unroll
    for (int i = 0; i < 2; ++i) {
        int n = nt * 128 + i * 64 + r0;
        int bb = n >> 10, uu = (n >> 5) & 31, vv = n & 31;
        bsrc[i] = ((bb * 34 + uu) * 34 + vv) * 1024 + g_ * 16;
    }
    int dstT = tid * 16;             // linear dest within a 4-KB chunk

    // ---- ds_read bases (R4 zero-conflict swizzle) ----
    int qs = (q ^ ((lr >> 1) & 3)) << 4;
    int Abase = (wr * 128 + lr) * 64 + qs;            // + mi*1024 imm
    int Bbase = 16384 + (wc * 64 + lr) * 64 + qs;     // + ni*1024 imm

    f32x4 acc[8][4];
#pragma unroll
    for (int mi = 0; mi < 8; ++mi)
#pragma unroll
        for (int ni = 0; ni < 4; ++ni) acc[mi][ni] = (f32x4){0.f, 0.f, 0.f, 0.f};

    auto STAGE = [&](int ks, int bufi) {   // 6 gload_lds: A 4 chunks, B 2
        int kl = ks >> 4;
        int kh = (kl * 11) >> 5;     // kl/3 for kl in [0,9)
        int kw = kl - 3 * kh;
        int bo = (kh * 34 + kw) * 1024 + (ks & 15) * 64;
        size_t ao = (size_t)ks * 64;
        char* L = lds + bufi * 24576;
#pragma unroll
        for (int i = 0; i < 4; ++i)
            __builtin_amdgcn_global_load_lds(GPTR(GA + asrcb + ao + (size_t)i * 589824),
                                             LPTR(L + i * 4096 + dstT), 16, 0, 0);
#pragma unroll
        for (int i = 0; i < 2; ++i)
            __builtin_amdgcn_global_load_lds(GPTR(GB + bsrc[i] + bo),
                                             LPTR(L + 16384 + i * 4096 + dstT), 16, 0, 0);
    };

    // prologue
    STAGE(0, 0);

    for (int t = 0; t < NT; ++t) {
        // barrier #1: all waves done reading buf (t+1)&1 (iter t-1's tile)
        __builtin_amdgcn_s_barrier();
        STAGE(t + 1 < NT ? t + 1 : NT - 1, (t + 1) & 1);
        // counted wait: t's 6 landed; t+1's 6 stay in flight under MFMA
        asm volatile("s_waitcnt vmcnt(6)" ::: "memory");
        __builtin_amdgcn_s_barrier();
        __builtin_amdgcn_sched_barrier(0);

        const char* Lc = lds + (t & 1) * 24576;
        short8 aF[8], bF[4];
#pragma unroll
        for (int mi = 0; mi < 8; ++mi) aF[mi] = *(const short8*)(Lc + Abase + mi * 1024);
#pragma unroll
        for (int ni = 0; ni < 4; ++ni) bF[ni] = *(const short8*)(Lc + Bbase + ni * 1024);

        __builtin_amdgcn_s_setprio(1);
#pragma unroll
        for (int mi = 0; mi < 8; ++mi)
#pragma unroll
            for (int ni = 0; ni < 4; ++ni)
                acc[mi][ni] = __builtin_amdgcn_mfma_f32_16x16x32_bf16(
                    aF[mi], bF[ni], acc[mi][ni], 0, 0, 0);
        __builtin_amdgcn_s_setprio(0);
    }
    asm volatile("s_waitcnt vmcnt(0)" ::: "memory");   // drain clamped stage

    // ---- epilogue: 4 acc regs per frag = 4 parities of one oc -> 2x2 quad ----
    const float s2 = 1.41421356237309515f;
#pragma unroll
    for (int mi = 0; mi < 8; ++mi) {
        int oc = mt * 64 + wr * 32 + mi * 4 + q;
        float bv = bias[oc];
#pragma unroll
        for (int ni = 0; ni < 4; ++ni) {
            int n = nt * 128 + wc * 64 + ni * 16 + lr;
            int b = n >> 10, u = (n >> 5) & 31, v = n & 31;
            float y0 = acc[mi][ni][0] + bv;
            float y1 = acc[mi][ni][1] + bv;
            float y2 = acc[mi][ni][2] + bv;
            float y3 = acc[mi][ni][3] + bv;
            y0 = (y0 >= 0.f ? y0 : 0.2f * y0) * s2;
            y1 = (y1 >= 0.f ? y1 : 0.2f * y1) * s2;
            y2 = (y2 >= 0.f ? y2 : 0.2f * y2) * s2;
            y3 = (y3 >= 0.f ? y3 : 0.2f * y3) * s2;
            size_t base = (((size_t)b * OC + oc) * OHW + 2 * u) * OHW + 2 * v;
            *(f32x2*)(out + base)       = (f32x2){y0, y1};   // row 2u:   p=(0,0),(0,1)
            *(f32x2*)(out + base + OHW) = (f32x2){y2, y3};   // row 2u+1: p=(1,0),(1,1)
        }
    }
}

// ---------------------------------------------------------------------------
extern "C" void kernel_launch(void* const* d_in, const int* in_sizes, int n_in,
                              void* d_out, int out_size, void* d_ws, size_t ws_size,
                              hipStream_t stream) {
    const float* x    = (const float*)d_in[0];
    const float* w    = (const float*)d_in[1];
    const float* bias = (const float*)d_in[2];
    float* out = (float*)d_out;

    __hip_bfloat16* xcl  = (__hip_bfloat16*)d_ws;
    __hip_bfloat16* Amat = (__hip_bfloat16*)((char*)d_ws + WS_AMAT_OFF);

    xprep<<<32 * 34, 256, 0, stream>>>(x, xcl);
    wtrans<<<(OC * IC) / 256, 256, 0, stream>>>(w, Amat);
    // grid: 4 M-tiles * 256 N-tiles = 1024 blocks, 256 threads (4 waves)
    gemm_conv<<<1024, 256, 0, stream>>>(Amat, xcl, bias, out);
}

// Round 14
// 296.566 us; speedup vs baseline: 1.1096x; 1.1096x over previous
//
#include <hip/hip_runtime.h>
#include <hip/hip_bf16.h>
#include <math.h>

// Problem constants
#define B_    32
#define IC    512
#define OC    256
#define HW    32
#define OHW   64

// ws layout:
//   xcl  at offset 0:          bf16 [32][34][34][512]  = 37,879,808 B (zero-padded channels-last)
//   Amat at offset 37,879,808: bf16 [1024][4608]       =  9,437,184 B
#define WS_AMAT_OFF 37879808ull

typedef __attribute__((ext_vector_type(8))) short short8;
typedef __attribute__((ext_vector_type(4))) float f32x4;
typedef __attribute__((ext_vector_type(2))) float f32x2;

#define GPTR(x) ((const __attribute__((address_space(1))) char*)(x))
#define LPTR(x) ((__attribute__((address_space(3))) char*)(x))

// ---------------------------------------------------------------------------
// Weight transform. M-row order (oc*4 + p): 4 consecutive C-rows per lane are
// the 4 parities of one oc -> coalesced 2x2 output quads in the epilogue.
__global__ __launch_bounds__(256) void wtrans(const float* __restrict__ w,
                                              __hip_bfloat16* __restrict__ Amat) {
    int t = blockIdx.x * blockDim.x + threadIdx.x;  // 131072 threads
    int ic = t & 511, oc = t >> 9;

    const float gain = 1.0f / sqrtf((float)(IC * 9));
    float wl[3][3];
    const float* wp = w + ((size_t)oc * IC + ic) * 9;
#pragma unroll
    for (int i = 0; i < 3; ++i)
#pragma unroll
        for (int j = 0; j < 3; ++j) wl[i][j] = wp[i * 3 + j] * gain;

    const float f1[4] = {1.f, 3.f, 3.f, 1.f};
    float g2[6][6];
#pragma unroll
    for (int s = 0; s < 6; ++s)
#pragma unroll
        for (int tt = 0; tt < 6; ++tt) {
            float acc = 0.f;
#pragma unroll
            for (int i = 0; i < 3; ++i)
#pragma unroll
                for (int j = 0; j < 3; ++j) {
                    int a = s - 2 + i, b = tt - 2 + j;
                    if (a >= 0 && a < 4 && b >= 0 && b < 4)
                        acc += wl[i][j] * f1[a] * f1[b] * 0.0625f;
                }
            g2[s][tt] = acc;
        }

#pragma unroll
    for (int pm = 0; pm < 2; ++pm)
#pragma unroll
        for (int pn = 0; pn < 2; ++pn)
#pragma unroll
            for (int k = 0; k < 3; ++k)
#pragma unroll
                for (int l = 0; l < 3; ++l) {
                    int p = pm * 2 + pn;
                    size_t idx = ((size_t)(oc * 4 + p) * 4608) + (k * 3 + l) * 512 + ic;
                    Amat[idx] = __float2bfloat16(g2[2 * k + 1 - pm][2 * l + 1 - pn]);
                }
}

// ---------------------------------------------------------------------------
// x (fp32 NCHW) -> xcl (bf16, [b][34][34][512], zero halo), via LDS transpose.
__global__ __launch_bounds__(256) void xprep(const float* __restrict__ x,
                                             __hip_bfloat16* __restrict__ xcl) {
    int blk = blockIdx.x;            // 32*34 blocks
    int b = blk / 34, h = blk % 34;
    __hip_bfloat16* orow = xcl + (size_t)(b * 34 + h) * 34 * 512;
    int t = threadIdx.x;
    bool hin = (h >= 1 && h <= 32);

    for (int i = t; i < 2 * 512; i += 256) {
        int wsel = i >> 9, ic = i & 511;
        orow[(size_t)(wsel * 33) * 512 + ic] = __float2bfloat16(0.f);
    }

    __shared__ float ls[16][33];
    int icl_r = t >> 5, wv_r = t & 31;
    int wv_w = t >> 3, icl_w = t & 7;

    for (int ic0 = 0; ic0 < 512; ic0 += 16) {
        __syncthreads();
#pragma unroll
        for (int pp = 0; pp < 2; ++pp) {
            int icll = icl_r + pp * 8;
            float v = 0.f;
            if (hin) v = x[(((size_t)b * IC + ic0 + icll) * HW + (h - 1)) * HW + wv_r];
            ls[icll][wv_r] = v;
        }
        __syncthreads();
#pragma unroll
        for (int pp = 0; pp < 2; ++pp) {
            int icll = icl_w + pp * 8;
            orow[(size_t)(wv_w + 1) * 512 + ic0 + icll] = __float2bfloat16(ls[icll][wv_w]);
        }
    }
}

// ---------------------------------------------------------------------------
// Implicit-GEMM, 256x256 tile, BK=32, 8 waves (2Mx4N), ring-4 LDS.
// R14 = R5 (best verified base, frag double-buffer) + DISTANCE-3 STAGING:
// STAGE(t+3) with vmcnt(8) keeps 12 loads in flight (R13 evidence: deeper
// outstanding queue sustains 18 B/cyc/CU vs R4's 14 — the staging pipe has
// headroom that distance-2 under-uses). Two barriers/tile for WAR safety:
//   STAGE(t+3)@iter t writes buf (t-1)&3; reads of tile t-1 were lgkm-
//   consumed before MFMA(t-1) (iter t-1), which precedes barrier#1 of
//   iter t -> no wave can still have reads of that buf in flight.
//   vmcnt(8) after STAGE(t+3): outstanding = {t+2, t+3} = 8 -> tile t+1
//   landed; barrier#2 makes it collective; READS(t+1) safe.
// + R8's XCD remap (FETCH 610->281 MB verified), R4 zero-conflict swizzle,
// 16x16x32 engine, T5 setprio, coalesced quad epilogue.
__global__ __launch_bounds__(512, 2) void gemm_conv(const __hip_bfloat16* __restrict__ Amat,
                                                    const __hip_bfloat16* __restrict__ xcl,
                                                    const float* __restrict__ bias,
                                                    float* __restrict__ out) {
    __shared__ __align__(1024) char lds[4 * 32768];

    const int NT = 144;
    int bid = blockIdx.x;
    // XCD remap (R8-verified): xcd = bid&7; all 4 mt of a slab co-resident.
    int mt = bid >> 7;                              // 0..3
    int nt = (bid & 7) * 16 + ((bid >> 3) & 15);    // 0..127
    int tid = threadIdx.x;
    int wid = tid >> 6;
    int lane = tid & 63;
    int wr = wid >> 2;               // 0..1  (M half)
    int wc = wid & 3;                // 0..3  (N quarter)
    int q = lane >> 4;               // k-granule
    int lr = lane & 15;

    // ---- staging source offsets (swizzle folded into global source) ----
    int rowS = tid >> 2;             // 0..127 (second load: +128)
    int slt = tid & 3;
    int fS = (rowS >> 1) & 3;
    int sgl = slt ^ fS;              // global slot fetched into LDS slot slt

    const char* GA = (const char*)Amat + (size_t)mt * 256 * 9216;
    int offA0 = rowS * 9216 + sgl * 16;
    int offA1 = (rowS + 128) * 9216 + sgl * 16;

    int n0 = nt * 256 + rowS;
    int b0i = n0 >> 10, u0 = (n0 >> 5) & 31, v0 = n0 & 31;
    int n1 = n0 + 128;
    int b1i = n1 >> 10, u1 = (n1 >> 5) & 31, v1 = n1 & 31;
    const char* GB = (const char*)xcl;
    int offB0 = ((b0i * 34 + u0) * 34 + v0) * 1024 + sgl * 16;
    int offB1 = ((b1i * 34 + u1) * 34 + v1) * 1024 + sgl * 16;

    int dA0 = wid * 1024;            // + lane*16 added by HW
    int dA1 = 8192 + wid * 1024;
    int dB0 = 16384 + wid * 1024;
    int dB1 = 16384 + 8192 + wid * 1024;

    // ---- ds_read bases (swizzle term (lr>>1)&3 is mi/ni-independent) ----
    int qs = (q ^ ((lr >> 1) & 3)) << 4;
    int A0 = (wr * 128 + lr) * 64 + qs;           // + mi*1024 imm
    int B0 = 16384 + (wc * 64 + lr) * 64 + qs;    // + ni*1024 imm

    f32x4 acc[8][4];
#pragma unroll
    for (int mi = 0; mi < 8; ++mi)
#pragma unroll
        for (int ni = 0; ni < 4; ++ni) acc[mi][ni] = (f32x4){0.f, 0.f, 0.f, 0.f};

    auto STAGE = [&](int ks, int bufi) {
        int kl = ks >> 4;
        int kh = (kl * 11) >> 5;     // kl/3 for kl in [0,9)
        int kw = kl - 3 * kh;
        int bko = (kh * 34 + kw) * 1024 + (ks & 15) * 64;
        int ao = ks * 64;
        char* L = lds + bufi * 32768;
        __builtin_amdgcn_global_load_lds(GPTR(GA + offA0 + ao), LPTR(L + dA0), 16, 0, 0);
        __builtin_amdgcn_global_load_lds(GPTR(GA + offA1 + ao), LPTR(L + dA1), 16, 0, 0);
        __builtin_amdgcn_global_load_lds(GPTR(GB + offB0 + bko), LPTR(L + dB0), 16, 0, 0);
        __builtin_amdgcn_global_load_lds(GPTR(GB + offB1 + bko), LPTR(L + dB1), 16, 0, 0);
    };

    short8 a0[8], b0[4], a1[8], b1[4];

#define READS(SETA, SETB, TT)                                                   \
    do {                                                                        \
        const char* L = lds + ((TT) & 3) * 32768;                               \
        _Pragma("unroll")                                                       \
        for (int mi = 0; mi < 8; ++mi) SETA[mi] = *(const short8*)(L + A0 + mi * 1024); \
        _Pragma("unroll")                                                       \
        for (int ni = 0; ni < 4; ++ni) SETB[ni] = *(const short8*)(L + B0 + ni * 1024); \
    } while (0)

#define MFMAS(SETA, SETB)                                                       \
    do {                                                                        \
        __builtin_amdgcn_s_setprio(1);                                          \
        _Pragma("unroll")                                                       \
        for (int mi = 0; mi < 8; ++mi)                                          \
            _Pragma("unroll")                                                   \
            for (int ni = 0; ni < 4; ++ni)                                      \
                acc[mi][ni] = __builtin_amdgcn_mfma_f32_16x16x32_bf16(          \
                    SETA[mi], SETB[ni], acc[mi][ni], 0, 0, 0);                  \
        __builtin_amdgcn_s_setprio(0);                                          \
    } while (0)

    // prologue: fill pipeline depth 3, read tile 0's fragments
    STAGE(0, 0);
    STAGE(1, 1);
    STAGE(2, 2);
    asm volatile("s_waitcnt vmcnt(8)" ::: "memory");   // tile 0 landed
    __builtin_amdgcn_s_barrier();
    __builtin_amdgcn_sched_barrier(0);
    READS(a0, b0, 0);

    for (int t = 0; t < NT; t += 2) {
        // ---- half 1: MFMA tile t (set0); reads t+1 -> set1; stage t+3 ----
        __builtin_amdgcn_s_barrier();                  // WAR fence for buf (t-1)&3
        STAGE(t + 3 < NT ? t + 3 : NT - 1, (t + 3) & 3);
        asm volatile("s_waitcnt vmcnt(8)" ::: "memory");   // tile t+1 landed
        __builtin_amdgcn_s_barrier();
        __builtin_amdgcn_sched_barrier(0);
        READS(a1, b1, t + 1);
        __builtin_amdgcn_sched_barrier(0);
        MFMAS(a0, b0);

        // ---- half 2: MFMA tile t+1 (set1); reads t+2 -> set0; stage t+4 ----
        __builtin_amdgcn_s_barrier();                  // WAR fence for buf t&3
        STAGE(t + 4 < NT ? t + 4 : NT - 1, (t + 4) & 3);
        asm volatile("s_waitcnt vmcnt(8)" ::: "memory");   // tile t+2 landed
        __builtin_amdgcn_s_barrier();
        __builtin_amdgcn_sched_barrier(0);
        READS(a0, b0, t + 2);
        __builtin_amdgcn_sched_barrier(0);
        MFMAS(a1, b1);
    }
    asm volatile("s_waitcnt vmcnt(0)" ::: "memory");   // drain clamped stages

    // ---- epilogue: 4 acc regs per frag = 4 parities of one oc -> 2x2 quad ----
    const float s2 = 1.41421356237309515f;
#pragma unroll
    for (int mi = 0; mi < 8; ++mi) {
        int oc = mt * 64 + wr * 32 + mi * 4 + q;
        float bv = bias[oc];
#pragma unroll
        for (int ni = 0; ni < 4; ++ni) {
            int n = nt * 256 + wc * 64 + ni * 16 + lr;
            int b = n >> 10, u = (n >> 5) & 31, v = n & 31;
            float y0 = acc[mi][ni][0] + bv;
            float y1 = acc[mi][ni][1] + bv;
            float y2 = acc[mi][ni][2] + bv;
            float y3 = acc[mi][ni][3] + bv;
            y0 = (y0 >= 0.f ? y0 : 0.2f * y0) * s2;
            y1 = (y1 >= 0.f ? y1 : 0.2f * y1) * s2;
            y2 = (y2 >= 0.f ? y2 : 0.2f * y2) * s2;
            y3 = (y3 >= 0.f ? y3 : 0.2f * y3) * s2;
            size_t base = (((size_t)b * OC + oc) * OHW + 2 * u) * OHW + 2 * v;
            *(f32x2*)(out + base)       = (f32x2){y0, y1};   // row 2u:   p=(0,0),(0,1)
            *(f32x2*)(out + base + OHW) = (f32x2){y2, y3};   // row 2u+1: p=(1,0),(1,1)
        }
    }
#undef READS
#undef MFMAS
}

// ---------------------------------------------------------------------------
extern "C" void kernel_launch(void* const* d_in, const int* in_sizes, int n_in,
                              void* d_out, int out_size, void* d_ws, size_t ws_size,
                              hipStream_t stream) {
    const float* x    = (const float*)d_in[0];
    const float* w    = (const float*)d_in[1];
    const float* bias = (const float*)d_in[2];
    float* out = (float*)d_out;

    __hip_bfloat16* xcl  = (__hip_bfloat16*)d_ws;
    __hip_bfloat16* Amat = (__hip_bfloat16*)((char*)d_ws + WS_AMAT_OFF);

    xprep<<<32 * 34, 256, 0, stream>>>(x, xcl);
    wtrans<<<(OC * IC) / 256, 256, 0, stream>>>(w, Amat);
    // grid: 4 M-tiles * 128 N-tiles = 512 blocks, 512 threads
    gemm_conv<<<512, 512, 0, stream>>>(Amat, xcl, bias, out);
}